// Round 2
// baseline (1358.815 us; speedup 1.0000x reference)
//
#include <hip/hip_runtime.h>
#include <hip/hip_bf16.h>
#include <math.h>
#include <stdint.h>

// Problem constants
constexpr int N_ROWS = 32768;
constexpr int K_DIM  = 4096;
constexpr int R_DIM  = 256;
constexpr int KP     = 3 * R_DIM;   // 768: split-K' for [hi|hi|lo] x [hi|lo|hi]
constexpr int KB     = K_DIM / 128; // 32 col-blocks in K2 grid.y

typedef __bf16 bf16x8 __attribute__((ext_vector_type(8)));
typedef float  f32x4  __attribute__((ext_vector_type(4)));
typedef unsigned short u16x8 __attribute__((ext_vector_type(8)));
typedef unsigned short u16x4 __attribute__((ext_vector_type(4)));

// ---- bf16 helpers (round-to-nearest-even; inputs are finite normals) ----
__device__ __forceinline__ unsigned short f2bf(float x) {
    unsigned u = __float_as_uint(x);
    u += 0x7fffu + ((u >> 16) & 1u);
    return (unsigned short)(u >> 16);
}
__device__ __forceinline__ float bf2f(unsigned short h) {
    return __uint_as_float((unsigned)h << 16);
}

// ---- async global->LDS, 16B per lane, LDS dest = wave-uniform base + lane*16
__device__ __forceinline__ void gl2lds16(const void* gptr, void* lptr) {
    __builtin_amdgcn_global_load_lds(
        (const __attribute__((address_space(1))) unsigned int*)gptr,
        (__attribute__((address_space(3))) unsigned int*)lptr,
        16, 0, 0);
}

// ===========================================================================
// MFMA NT GEMM for K2: M[m,n] = sum_k A[m,k]*B[n,k], bf16 k-major, C fp32.
// 128x128 tile, BK=32, 256 threads = 4 waves (2x2 of 64x64), 16x16x32 MFMA.
// Epilogue additionally emits per-row softmax partials over this block's
// 128 cols: Pm[row][by] = max, Ps[row][by] = sum exp(x - max).
// ===========================================================================
__global__ __launch_bounds__(256)
void gemm_mfma_nt(const unsigned short* __restrict__ A,
                  const unsigned short* __restrict__ B,
                  float* __restrict__ C,
                  float* __restrict__ Pm, float* __restrict__ Ps,
                  int M, int N, int Kc)
{
    __shared__ __align__(16) unsigned short As[128 * 32];
    __shared__ __align__(16) unsigned short Bs[128 * 32];
    __shared__ float pm_s[128][2], ps_s[128][2];

    const int tid  = threadIdx.x;
    const int wave = tid >> 6, lane = tid & 63;
    const int wm = wave >> 1, wn = wave & 1;
    const long m0 = (long)blockIdx.x * 128;
    const long n0 = (long)blockIdx.y * 128;

    f32x4 acc[4][4] = {};

    const int srow  = lane >> 2;        // 0..15 within 16-row chunk
    const int skoff = (lane & 3) * 8;   // bf16 elem offset within 32-wide row
    const int c0 = wave, c1 = wave + 4; // each wave stages 2 chunks per tile
    const int kq = (lane >> 4) * 8;     // frag k-offset 0,8,16,24
    const int mr = lane & 15;

    for (int k0 = 0; k0 < Kc; k0 += 32) {
        gl2lds16(A + (m0 + c0 * 16 + srow) * (long)Kc + k0 + skoff, &As[c0 * 512]);
        gl2lds16(A + (m0 + c1 * 16 + srow) * (long)Kc + k0 + skoff, &As[c1 * 512]);
        gl2lds16(B + (n0 + c0 * 16 + srow) * (long)Kc + k0 + skoff, &Bs[c0 * 512]);
        gl2lds16(B + (n0 + c1 * 16 + srow) * (long)Kc + k0 + skoff, &Bs[c1 * 512]);
        __syncthreads();

        bf16x8 af[4], bfr[4];
#pragma unroll
        for (int t = 0; t < 4; ++t) {
            af[t]  = *(const bf16x8*)&As[(wm * 64 + t * 16 + mr) * 32 + kq];
            bfr[t] = *(const bf16x8*)&Bs[(wn * 64 + t * 16 + mr) * 32 + kq];
        }
#pragma unroll
        for (int i = 0; i < 4; ++i)
#pragma unroll
            for (int j = 0; j < 4; ++j)
                acc[i][j] = __builtin_amdgcn_mfma_f32_16x16x32_bf16(
                    af[i], bfr[j], acc[i][j], 0, 0, 0);
        __syncthreads();
    }

    // C/D layout: col = lane&15, row = (lane>>4)*4 + reg
    const int col = lane & 15, rquad = (lane >> 4) * 4;
#pragma unroll
    for (int i = 0; i < 4; ++i) {
        const long mrow = m0 + wm * 64 + i * 16 + rquad;
#pragma unroll
        for (int j = 0; j < 4; ++j) {
            float* p = C + mrow * (long)N + n0 + wn * 64 + j * 16 + col;
#pragma unroll
            for (int r = 0; r < 4; ++r) p[(long)r * N] = acc[i][j][r];
        }
    }

    // ---- softmax partials over this block's 128 cols, per row --------------
#pragma unroll
    for (int i = 0; i < 4; ++i) {
#pragma unroll
        for (int r = 0; r < 4; ++r) {
            float mx = fmaxf(fmaxf(acc[i][0][r], acc[i][1][r]),
                             fmaxf(acc[i][2][r], acc[i][3][r]));
#pragma unroll
            for (int off = 1; off < 16; off <<= 1)
                mx = fmaxf(mx, __shfl_xor(mx, off));
            float sm = 0.f;
#pragma unroll
            for (int j = 0; j < 4; ++j) sm += __expf(acc[i][j][r] - mx);
#pragma unroll
            for (int off = 1; off < 16; off <<= 1)
                sm += __shfl_xor(sm, off);
            if (mr == 0) {
                const int rw = wm * 64 + i * 16 + rquad + r;
                pm_s[rw][wn] = mx;
                ps_s[rw][wn] = sm;
            }
        }
    }
    __syncthreads();
    if (tid < 128) {
        const float ma = pm_s[tid][0], mb = pm_s[tid][1];
        const float mx = fmaxf(ma, mb);
        const float s  = ps_s[tid][0] * __expf(ma - mx) +
                         ps_s[tid][1] * __expf(mb - mx);
        Pm[(m0 + tid) * KB + blockIdx.y] = mx;
        Ps[(m0 + tid) * KB + blockIdx.y] = s;
    }
}

// ===========================================================================
// Combine per-block softmax partials -> per-row (max, 1/sum).
// One thread per row; 32 partials per row, contiguous.
// ===========================================================================
__global__ __launch_bounds__(256)
void finalize_ms(const float* __restrict__ Pm, const float* __restrict__ Ps,
                 float* __restrict__ SMm, float* __restrict__ SMi)
{
    const long row = (long)blockIdx.x * 256 + threadIdx.x;
    const float4* pm = (const float4*)(Pm + row * KB);
    const float4* ps = (const float4*)(Ps + row * KB);
    float4 v[8];
    float mx = -3.4e38f;
#pragma unroll
    for (int q = 0; q < 8; ++q) {
        v[q] = pm[q];
        mx = fmaxf(mx, fmaxf(fmaxf(v[q].x, v[q].y), fmaxf(v[q].z, v[q].w)));
    }
    float s = 0.f;
#pragma unroll
    for (int q = 0; q < 8; ++q) {
        float4 w = ps[q];
        s += w.x * __expf(v[q].x - mx) + w.y * __expf(v[q].y - mx) +
             w.z * __expf(v[q].z - mx) + w.w * __expf(v[q].w - mx);
    }
    SMm[row] = mx;
    SMi[row] = 1.f / s;
}

// ===========================================================================
// Single-pass fused softmax-apply + PV:
//   A[n,k] = exp(M[n,k]-m_n) * inv_n   (written in place over M)
//   C[n,r] = (sum_k exp(M-m) * LT[r,k]) * inv_n   (bf16 MFMA)
// Grid: N_ROWS/32 blocks x 256 threads (4 waves, each 32 rows x 64 cols).
// BK=32 k-tiles, double-buffered LDS, next-tile loads issued before MFMA.
// LT is R_DIM x K_DIM bf16 k-major, L2-resident (2 MB).
// ===========================================================================
__global__ __launch_bounds__(256)
void softmax_av_sp(float* __restrict__ Mio,
                   const unsigned short* __restrict__ LT,
                   const float* __restrict__ SMm, const float* __restrict__ SMi,
                   float* __restrict__ C)
{
    __shared__ __align__(16) unsigned short Bs[2][R_DIM * 32]; // 2 x 16 KiB
    __shared__ __align__(16) unsigned short As[2][32 * 32];    // 2 x  2 KiB
    __shared__ float sm_m[32], sm_inv[32];

    const int tid  = threadIdx.x;
    const int wave = tid >> 6, lane = tid & 63;
    const long m0 = (long)blockIdx.x * 32;

    if (tid < 32) { sm_m[tid] = SMm[m0 + tid]; sm_inv[tid] = SMi[m0 + tid]; }
    __syncthreads();

    const int mr   = lane & 15;
    const int kq16 = (lane >> 4) * 16;          // 16B frag slot within 64B row
    const int arow = tid >> 3;                  // 0..31
    const int acol = (tid & 7) * 4;             // 0..28
    const int abyte = (arow * 64 + (tid & 7) * 8) ^ ((arow & 3) << 4);
    const float myM = sm_m[arow], myI = sm_inv[arow];
    float* const arp = Mio + (m0 + arow) * (long)K_DIM + acol;

    f32x4 acc[2][4] = {};

    // stage LT k-tile into Bs[buf] (source pre-swizzled, dest linear)
    auto stage_B = [&](int buf, int kk0) {
#pragma unroll
        for (int w = 0; w < 4; ++w) {
            const int rloc = wave * 64 + w * 16 + (lane >> 2);
            const int sb   = ((lane & 3) * 16) ^ ((rloc & 3) << 4);
            gl2lds16((const char*)LT + (long)rloc * (K_DIM * 2) + (long)kk0 * 2 + sb,
                     &Bs[buf][(wave * 64 + w * 16) * 32]);
        }
    };
    // exp + global A write + swizzled LDS As write
    auto emit_A = [&](int buf, int kk0, float4 v) {
        const float e0 = __expf(v.x - myM), e1 = __expf(v.y - myM);
        const float e2 = __expf(v.z - myM), e3 = __expf(v.w - myM);
        *(float4*)(arp + kk0) = make_float4(e0 * myI, e1 * myI, e2 * myI, e3 * myI);
        u16x4 u;
        u[0] = f2bf(e0); u[1] = f2bf(e1); u[2] = f2bf(e2); u[3] = f2bf(e3);
        *(u16x4*)((char*)As[buf] + abyte) = u;
    };

    // prologue: tile 0
    stage_B(0, 0);
    emit_A(0, 0, *(const float4*)(arp + 0));
    __syncthreads();

    int cur = 0;
    for (int t = 0; t < K_DIM / 32; ++t) {
        const int nxt = cur ^ 1;
        float4 vn;
        const bool has_next = (t < K_DIM / 32 - 1);
        if (has_next) {
            stage_B(nxt, (t + 1) * 32);
            vn = *(const float4*)(arp + (t + 1) * 32);
        }

        bf16x8 af[2], bfr[4];
#pragma unroll
        for (int q = 0; q < 2; ++q) {
            const int ar = q * 16 + mr;
            af[q] = *(const bf16x8*)((const char*)As[cur] +
                    ((ar * 64 + kq16) ^ ((ar & 3) << 4)));
        }
#pragma unroll
        for (int q = 0; q < 4; ++q) {
            const int br = wave * 64 + q * 16 + mr;
            bfr[q] = *(const bf16x8*)((const char*)Bs[cur] +
                     ((br * 64 + kq16) ^ ((br & 3) << 4)));
        }
#pragma unroll
        for (int i = 0; i < 2; ++i)
#pragma unroll
            for (int j = 0; j < 4; ++j)
                acc[i][j] = __builtin_amdgcn_mfma_f32_16x16x32_bf16(
                    af[i], bfr[j], acc[i][j], 0, 0, 0);

        if (has_next) emit_A(nxt, (t + 1) * 32, vn);
        __syncthreads();
        cur = nxt;
    }

    // epilogue: scale by 1/s, write C
    const int col = lane & 15, rquad = (lane >> 4) * 4;
#pragma unroll
    for (int i = 0; i < 2; ++i) {
        const int lrow0 = i * 16 + rquad;
#pragma unroll
        for (int j = 0; j < 4; ++j) {
            float* p = C + (m0 + lrow0) * (long)R_DIM + wave * 64 + j * 16 + col;
#pragma unroll
            for (int r = 0; r < 4; ++r)
                p[(long)r * R_DIM] = acc[i][j][r] * sm_inv[lrow0 + r];
        }
    }
}

// ===========================================================================
// Prep kernels
// ===========================================================================
// B' = [L_hi | L_lo | L_hi]  (K_DIM x 768)
__global__ __launch_bounds__(256)
void prep_B(const float* __restrict__ L, unsigned short* __restrict__ Bp)
{
    const long i = (long)blockIdx.x * 256 + threadIdx.x;   // over K_DIM*R_DIM
    const long k = i >> 8; const int r = (int)(i & 255);
    const float x = L[i];
    const unsigned short hi = f2bf(x);
    const unsigned short lo = f2bf(x - bf2f(hi));
    unsigned short* row = Bp + k * KP;
    row[r] = hi; row[R_DIM + r] = lo; row[2 * R_DIM + r] = hi;
}

// LT[r][k] = bf16(L[k][r])  (256 x 4096) — coalesced writes
__global__ __launch_bounds__(256)
void prep_LT(const float* __restrict__ L, unsigned short* __restrict__ LT)
{
    const long i = (long)blockIdx.x * 256 + threadIdx.x;   // over R_DIM*K_DIM
    const long r = i >> 12; const long k = i & 4095;
    LT[r * K_DIM + k] = f2bf(L[k * R_DIM + r]);
}

// ===========================================================================
// fp32 VALU GEMM — K1 base + fallback path.
// ===========================================================================
template<bool BT>
__global__ __launch_bounds__(256)
void gemm128(const float* __restrict__ A, const float* __restrict__ B,
             float* __restrict__ C, int M, int N, int Kc)
{
    __shared__ __align__(16) float Asl[16][132];
    __shared__ __align__(16) float Bsl[16][132];

    const int tid = threadIdx.x;
    const int tx = tid & 15, ty = tid >> 4;
    const long m0 = (long)blockIdx.x * 128;
    const long n0 = (long)blockIdx.y * 128;

    float acc[8][8];
#pragma unroll
    for (int i = 0; i < 8; ++i)
#pragma unroll
        for (int j = 0; j < 8; ++j) acc[i][j] = 0.f;

    for (int k0 = 0; k0 < Kc; k0 += 16) {
#pragma unroll
        for (int q = 0; q < 2; ++q) {
            int fi = tid + 256 * q, row = fi >> 2, col = (fi & 3) * 4;
            float4 v = *(const float4*)(A + (m0 + row) * (long)Kc + k0 + col);
            Asl[col + 0][row] = v.x; Asl[col + 1][row] = v.y;
            Asl[col + 2][row] = v.z; Asl[col + 3][row] = v.w;
        }
        if (BT) {
#pragma unroll
            for (int q = 0; q < 2; ++q) {
                int fi = tid + 256 * q, row = fi >> 2, col = (fi & 3) * 4;
                float4 v = *(const float4*)(B + (n0 + row) * (long)Kc + k0 + col);
                Bsl[col + 0][row] = v.x; Bsl[col + 1][row] = v.y;
                Bsl[col + 2][row] = v.z; Bsl[col + 3][row] = v.w;
            }
        } else {
#pragma unroll
            for (int q = 0; q < 2; ++q) {
                int fi = tid + 256 * q, row = fi >> 5, col = (fi & 31) * 4;
                float4 v = *(const float4*)(B + (k0 + row) * (long)N + n0 + col);
                *(float4*)&Bsl[row][col] = v;
            }
        }
        __syncthreads();
#pragma unroll
        for (int kk = 0; kk < 16; ++kk) {
            float a[8], b[8];
            *(float4*)&a[0] = *(const float4*)&Asl[kk][ty * 8];
            *(float4*)&a[4] = *(const float4*)&Asl[kk][ty * 8 + 4];
            *(float4*)&b[0] = *(const float4*)&Bsl[kk][tx * 8];
            *(float4*)&b[4] = *(const float4*)&Bsl[kk][tx * 8 + 4];
#pragma unroll
            for (int i = 0; i < 8; ++i)
#pragma unroll
                for (int j = 0; j < 8; ++j)
                    acc[i][j] = fmaf(a[i], b[j], acc[i][j]);
        }
        __syncthreads();
    }
#pragma unroll
    for (int i = 0; i < 8; ++i) {
        float* p = C + (m0 + ty * 8 + i) * (long)N + n0 + tx * 8;
        *(float4*)p       = make_float4(acc[i][0], acc[i][1], acc[i][2], acc[i][3]);
        *(float4*)(p + 4) = make_float4(acc[i][4], acc[i][5], acc[i][6], acc[i][7]);
    }
}

// ===========================================================================
// K1 with fused split-write: P = A@B (fp32 VALU), epilogue writes
// Ap = [P_hi | P_hi | P_lo] directly (no P materialization).
// ===========================================================================
__global__ __launch_bounds__(256)
void gemm128_hl(const float* __restrict__ A, const float* __restrict__ B,
                unsigned short* __restrict__ Ap, int M, int N, int Kc)
{
    __shared__ __align__(16) float Asl[16][132];
    __shared__ __align__(16) float Bsl[16][132];

    const int tid = threadIdx.x;
    const int tx = tid & 15, ty = tid >> 4;
    const long m0 = (long)blockIdx.x * 128;
    const long n0 = (long)blockIdx.y * 128;

    float acc[8][8];
#pragma unroll
    for (int i = 0; i < 8; ++i)
#pragma unroll
        for (int j = 0; j < 8; ++j) acc[i][j] = 0.f;

    for (int k0 = 0; k0 < Kc; k0 += 16) {
#pragma unroll
        for (int q = 0; q < 2; ++q) {
            int fi = tid + 256 * q, row = fi >> 2, col = (fi & 3) * 4;
            float4 v = *(const float4*)(A + (m0 + row) * (long)Kc + k0 + col);
            Asl[col + 0][row] = v.x; Asl[col + 1][row] = v.y;
            Asl[col + 2][row] = v.z; Asl[col + 3][row] = v.w;
        }
#pragma unroll
        for (int q = 0; q < 2; ++q) {
            int fi = tid + 256 * q, row = fi >> 5, col = (fi & 31) * 4;
            float4 v = *(const float4*)(B + (k0 + row) * (long)N + n0 + col);
            *(float4*)&Bsl[row][col] = v;
        }
        __syncthreads();
#pragma unroll
        for (int kk = 0; kk < 16; ++kk) {
            float a[8], b[8];
            *(float4*)&a[0] = *(const float4*)&Asl[kk][ty * 8];
            *(float4*)&a[4] = *(const float4*)&Asl[kk][ty * 8 + 4];
            *(float4*)&b[0] = *(const float4*)&Bsl[kk][tx * 8];
            *(float4*)&b[4] = *(const float4*)&Bsl[kk][tx * 8 + 4];
#pragma unroll
            for (int i = 0; i < 8; ++i)
#pragma unroll
                for (int j = 0; j < 8; ++j)
                    acc[i][j] = fmaf(a[i], b[j], acc[i][j]);
        }
        __syncthreads();
    }
#pragma unroll
    for (int i = 0; i < 8; ++i) {
        const long row = m0 + ty * 8 + i;
        const int  cb  = (int)n0 + tx * 8;
        u16x8 vh, vl;
#pragma unroll
        for (int j = 0; j < 8; ++j) {
            const float x = acc[i][j];
            const unsigned short hi = f2bf(x);
            vh[j] = hi;
            vl[j] = f2bf(x - bf2f(hi));
        }
        unsigned short* rp = Ap + row * KP;
        *(u16x8*)(rp + cb)             = vh;
        *(u16x8*)(rp + R_DIM + cb)     = vh;
        *(u16x8*)(rp + 2 * R_DIM + cb) = vl;
    }
}

// ---------------------------------------------------------------------------
// In-place row softmax (fallback path only)
// ---------------------------------------------------------------------------
__global__ __launch_bounds__(256)
void softmax_rows(float* __restrict__ Mio)
{
    const long n  = blockIdx.x;
    float* row    = Mio + n * (long)K_DIM;
    const int tid = threadIdx.x;

    float4 v[4];
    float lmax = -3.4e38f;
#pragma unroll
    for (int q = 0; q < 4; ++q) {
        v[q] = ((const float4*)row)[tid + 256 * q];
        lmax = fmaxf(lmax, fmaxf(fmaxf(v[q].x, v[q].y), fmaxf(v[q].z, v[q].w)));
    }
    __shared__ float redmax[4], redsum[4];
#pragma unroll
    for (int off = 32; off > 0; off >>= 1)
        lmax = fmaxf(lmax, __shfl_xor(lmax, off));
    if ((tid & 63) == 0) redmax[tid >> 6] = lmax;
    __syncthreads();
    const float gmax = fmaxf(fmaxf(redmax[0], redmax[1]), fmaxf(redmax[2], redmax[3]));

    float lsum = 0.f;
#pragma unroll
    for (int q = 0; q < 4; ++q) {
        v[q].x = __expf(v[q].x - gmax); v[q].y = __expf(v[q].y - gmax);
        v[q].z = __expf(v[q].z - gmax); v[q].w = __expf(v[q].w - gmax);
        lsum += v[q].x + v[q].y + v[q].z + v[q].w;
    }
#pragma unroll
    for (int off = 32; off > 0; off >>= 1)
        lsum += __shfl_xor(lsum, off);
    if ((tid & 63) == 0) redsum[tid >> 6] = lsum;
    __syncthreads();
    const float inv = 1.f / (redsum[0] + redsum[1] + redsum[2] + redsum[3]);
#pragma unroll
    for (int q = 0; q < 4; ++q) {
        v[q].x *= inv; v[q].y *= inv; v[q].z *= inv; v[q].w *= inv;
        ((float4*)row)[tid + 256 * q] = v[q];
    }
}

// ===========================================================================
extern "C" void kernel_launch(void* const* d_in, const int* in_sizes, int n_in,
                              void* d_out, int out_size, void* d_ws, size_t ws_size,
                              hipStream_t stream)
{
    const float* H  = (const float*)d_in[0];
    const float* L  = (const float*)d_in[1];
    const float* Wi = (const float*)d_in[2];

    float* Cout = (float*)d_out;                           // N x R
    float* Aout = (float*)d_out + (size_t)N_ROWS * R_DIM;  // N x K

    const size_t szAp = (size_t)N_ROWS * KP * 2;    // 48 MiB
    const size_t szBp = (size_t)K_DIM * KP * 2;     //  6 MiB
    const size_t szLT = (size_t)R_DIM * K_DIM * 2;  //  2 MiB
    const size_t szPm = (size_t)N_ROWS * KB * 4;    //  4 MiB
    const size_t szPs = (size_t)N_ROWS * KB * 4;    //  4 MiB
    const size_t szSM = (size_t)N_ROWS * 4;         // 128 KiB

    if (ws_size >= szAp + szBp + szLT + szPm + szPs + 2 * szSM) {
        char* w = (char*)d_ws;
        unsigned short* Ap = (unsigned short*)w;                 w += szAp;
        unsigned short* Bp = (unsigned short*)w;                 w += szBp;
        unsigned short* LT = (unsigned short*)w;                 w += szLT;
        float* Pm  = (float*)w;                                  w += szPm;
        float* Ps  = (float*)w;                                  w += szPs;
        float* SMm = (float*)w;                                  w += szSM;
        float* SMi = (float*)w;

        // K1: P = H@W_I (fp32 VALU), split [hi|hi|lo] written directly to Ap
        gemm128_hl<<<dim3(N_ROWS / 128, R_DIM / 128), 256, 0, stream>>>(
            H, Wi, Ap, N_ROWS, R_DIM, R_DIM);
        // Prep split B operand + transposed bf16 L
        prep_B<<<dim3((K_DIM * R_DIM) / 256), 256, 0, stream>>>(L, Bp);
        prep_LT<<<dim3((R_DIM * K_DIM) / 256), 256, 0, stream>>>(L, LT);
        // K2: logits M = A'·B'^T (3-term split bf16 MFMA) + softmax partials
        gemm_mfma_nt<<<dim3(N_ROWS / 128, K_DIM / 128), 256, 0, stream>>>(
            Ap, Bp, Aout, Pm, Ps, N_ROWS, K_DIM, KP);
        // combine partials -> per-row (max, 1/sum)
        finalize_ms<<<dim3(N_ROWS / 256), 256, 0, stream>>>(Pm, Ps, SMm, SMi);
        // single-pass: A = softmax applied in place; C = A@L
        softmax_av_sp<<<dim3(N_ROWS / 32), 256, 0, stream>>>(
            Aout, LT, SMm, SMi, Cout);
    } else {
        // Fallback: round-1 fp32 path
        gemm128<false><<<dim3(N_ROWS / 128, R_DIM / 128), 256, 0, stream>>>(
            H, Wi, Cout, N_ROWS, R_DIM, R_DIM);
        gemm128<true><<<dim3(N_ROWS / 128, K_DIM / 128), 256, 0, stream>>>(
            Cout, L, Aout, N_ROWS, K_DIM, R_DIM);
        softmax_rows<<<dim3(N_ROWS), 256, 0, stream>>>(Aout);
        gemm128<false><<<dim3(N_ROWS / 128, R_DIM / 128), 256, 0, stream>>>(
            Aout, L, Cout, N_ROWS, R_DIM, K_DIM);
    }
}